// Round 13
// baseline (232.150 us; speedup 1.0000x reference)
//
#include <hip/hip_runtime.h>
#include <math.h>

#define BB 8
#define NN 2048
#define FIN 128
#define FOUT 64
#define TI 16
#define TJ 512
#define TJP (TJ + 8)      // +8 bf16 = 16B row pad: A-frag ds_read_b128 bank skew
#define NTILE (NN / TJ)   // 4 j-tiles, looped INSIDE the block (R16: fused)

typedef short bf16x8 __attribute__((ext_vector_type(8)));
typedef float f32x4 __attribute__((ext_vector_type(4)));

// exp(tanh(z)) = exp((u-1)/(u+1)), u = e^{2z}; v_rcp instead of precise div.
__device__ __forceinline__ float exp_tanh(float z) {
    float zc = fminf(fmaxf(z, -15.f), 15.f);
    float u = __expf(zc + zc);
    float tn = (u - 1.f) * __builtin_amdgcn_rcpf(u + 1.f);
    return __expf(tn);
}

__device__ __forceinline__ unsigned short f2bf(float x) {
    union { float f; unsigned u; } v; v.f = x;
    unsigned r = v.u + 0x7FFF + ((v.u >> 16) & 1);   // round-to-nearest-even
    return (unsigned short)(r >> 16);
}

// K1: h = x @ W -> bf16 TRANSPOSED ht[b][c][n]; f1 = h.a1, f2 = h.a2.
// (verbatim from the harness-verified kernel)
__global__ __launch_bounds__(256, 2) void gat_k1(const float* __restrict__ x,
                                                 const float* __restrict__ W,
                                                 const float* __restrict__ a,
                                                 unsigned short* __restrict__ ht,
                                                 float* __restrict__ f1,
                                                 float* __restrict__ f2) {
    __shared__ __attribute__((aligned(16))) float Wl[FIN][FOUT];  // 32 KB
    __shared__ __attribute__((aligned(16))) float xs[16][FIN];    // 8 KB
    int t = threadIdx.x;

    const float4* W4 = (const float4*)W;
    float4* Wl4 = (float4*)&Wl[0][0];
#pragma unroll
    for (int kk = 0; kk < 8; ++kk) Wl4[t + 256 * kk] = W4[t + 256 * kk];

    size_t row0 = (size_t)blockIdx.x * 16;
    const float4* x4 = (const float4*)(x + row0 * FIN);
    float4* xs4 = (float4*)&xs[0][0];
#pragma unroll
    for (int kk = 0; kk < 2; ++kk) xs4[t + 256 * kk] = x4[t + 256 * kk];
    __syncthreads();

    int c = t & 63;
    int rq = t >> 6;
    float acc[4] = {0.f, 0.f, 0.f, 0.f};
#pragma unroll 8
    for (int k = 0; k < FIN; ++k) {
        float wv = Wl[k][c];
        acc[0] = fmaf(xs[rq][k], wv, acc[0]);
        acc[1] = fmaf(xs[rq + 4][k], wv, acc[1]);
        acc[2] = fmaf(xs[rq + 8][k], wv, acc[2]);
        acc[3] = fmaf(xs[rq + 12][k], wv, acc[3]);
    }
    float a1c = a[c], a2c = a[FOUT + c];
#pragma unroll
    for (int m = 0; m < 4; ++m) {
        size_t bn = row0 + rq + 4 * m;
        int b = (int)(bn >> 11);
        int n = (int)(bn & 2047);
        ht[((size_t)b * FOUT + c) * NN + n] = f2bf(acc[m]);
        float p1 = acc[m] * a1c;
        float p2 = acc[m] * a2c;
#pragma unroll
        for (int off = 32; off > 0; off >>= 1) {
            p1 += __shfl_down(p1, off, 64);
            p2 += __shfl_down(p2, off, 64);
        }
        if (c == 0) { f1[bn] = p1; f2[bn] = p2; }
    }
}

// K2f R17: R16 fused structure + ADJ PREFETCH PIPELINE.
// Evidence ledger: R15 (adj 32x traffic cut) = +28us -> not BW-bound.
// R16 (atomics/k3/memset deleted) = -4us -> not epilogue-bound.
// Surviving theory: adj LATENCY EXPOSURE -- loads issue, then only a
// f2s-stage + 1 barrier (<~300cy) before vmcnt consumption; ~900cy HBM
// latency minus that is a per-tile stall, and 16 waves/CU (grid=4
// blocks/CU exactly) can't cover it (2KB in flight/CU ~ 1.4 TB/s eff).
// Fix: double-buffer avreg -- issue tile jt+1's 8x int4 BEFORE p-phase
// and MFMA of tile jt (~2000cy of cover). jt loop fully unrolled so the
// [jt&1] buffer index is compile-time (no scratch, rule #20). Est ~115
// VGPR < 128 cliff -> 4 waves/SIMD retained. Barriers/LDS unchanged
// from R16's verified hazard structure (prefetch is register-only).
__global__ __launch_bounds__(256) void gat_k2f(const int* __restrict__ adj,
                                               const unsigned short* __restrict__ ht,
                                               const float* __restrict__ f1,
                                               const float* __restrict__ f2,
                                               float* __restrict__ out) {
    __shared__ __attribute__((aligned(16))) unsigned short pb[TI][TJP];  // 16.6 KB
    __shared__ __attribute__((aligned(16))) float f2s[TJ];               // 2 KB
    __shared__ float f1s[TI];
    __shared__ float rsw[2][TI];                                         // 128 B

    int t = threadIdx.x;
    int i0 = blockIdx.x * TI;
    int b = blockIdx.y;

    int lane = t & 63;
    int w = t >> 6;         // wave id -> c-tile
    int mrow = lane & 15;   // MFMA m / n index
    int quad = lane >> 4;   // MFMA k-quad

    // p-phase mapping: thread handles j4 = t&127 (float4 group), rows r0+2kk
    int j4 = t & 127;
    int r0 = t >> 7;        // wave-uniform

    if (t < TI) f1s[t] = f1[(size_t)b * NN + i0 + t];
    __syncthreads();

    float f1r[8];
    float ps[8];
#pragma unroll
    for (int kk = 0; kk < 8; ++kk) {
        f1r[kk] = f1s[r0 + 2 * kk];
        ps[kk] = 0.f;
    }
    f32x4 acc = {0.f, 0.f, 0.f, 0.f};

    // per-thread adj base: row (i0 + r0 + 2kk), col group 4*j4
    const int* adjrow = adj + (((size_t)b * NN + i0) * NN) + 4 * j4;

    // ---- prologue: issue tile 0's adj loads ----
    int4 avreg[2][8];
#pragma unroll
    for (int kk = 0; kk < 8; ++kk)
        avreg[0][kk] = *(const int4*)(adjrow + (size_t)(r0 + 2 * kk) * NN);

#pragma unroll
    for (int jt = 0; jt < NTILE; ++jt) {   // constant trip, fully unrolled
        int j0 = jt * TJ;
        int cur = jt & 1;

        // stage this j-tile's f2 slice (512 floats, L2-resident)
        ((float2*)f2s)[t] = ((const float2*)(f2 + (size_t)b * NN + j0))[t];

        // ---- prefetch next tile's adj (register-only, hides under compute) ----
        if (jt + 1 < NTILE) {
#pragma unroll
            for (int kk = 0; kk < 8; ++kk)
                avreg[cur ^ 1][kk] = *(const int4*)(
                    adjrow + (size_t)(r0 + 2 * kk) * NN + (j0 + TJ));
        }
        __syncthreads();   // WAR barrier for pb/f2s reuse (R16-verified order)

        // ---- p-phase: mask -> exp(tanh) -> bf16 into LDS ----
        float4 fv = ((const float4*)f2s)[j4];
#pragma unroll
        for (int kk = 0; kk < 8; ++kk) {
            int4 av = avreg[cur][kk];
            float f1i = f1r[kk];
            float4 p;
            p.x = (av.x > 0) ? exp_tanh(f1i + fv.x) : 0.f;
            p.y = (av.y > 0) ? exp_tanh(f1i + fv.y) : 0.f;
            p.z = (av.z > 0) ? exp_tanh(f1i + fv.z) : 0.f;
            p.w = (av.w > 0) ? exp_tanh(f1i + fv.w) : 0.f;
            ps[kk] += p.x + p.y + p.z + p.w;   // running rowsum across jt
            ushort4 pk;
            pk.x = f2bf(p.x); pk.y = f2bf(p.y);
            pk.z = f2bf(p.z); pk.w = f2bf(p.w);
            *(ushort4*)&pb[r0 + 2 * kk][4 * j4] = pk;
        }
        __syncthreads();

        // ---- PV on matrix pipe: 16 chunks of K=32, acc chained over jt ----
        const unsigned short* hp =
            ht + ((size_t)b * FOUT + w * 16 + mrow) * NN + j0 + 8 * quad;
        const unsigned short* prow = &pb[mrow][8 * quad];
#pragma unroll 4
        for (int ch = 0; ch < TJ / 32; ++ch) {
            bf16x8 af = *(const bf16x8*)(prow + 32 * ch);
            bf16x8 bf = *(const bf16x8*)(hp + 32 * ch);
            acc = __builtin_amdgcn_mfma_f32_16x16x32_bf16(af, bf, acc, 0, 0, 0);
        }
    }

    // ---- rowsum: in-wave shfl reduce, 2 wave-partials per row via LDS ----
#pragma unroll
    for (int kk = 0; kk < 8; ++kk) {
        float s = ps[kk];
#pragma unroll
        for (int off = 32; off > 0; off >>= 1) s += __shfl_down(s, off, 64);
        if (lane == 0) rsw[w & 1][r0 + 2 * kk] = s;
    }
    __syncthreads();

    // ---- epilogue: final out = elu(acc / rowsum), D-frag mapping verified ----
    float* op = out + ((size_t)b * NN + i0) * FOUT + w * 16 + mrow;
#pragma unroll
    for (int u = 0; u < 4; ++u) {
        int row = quad * 4 + u;
        float rinv = __builtin_amdgcn_rcpf(rsw[0][row] + rsw[1][row]);
        float sx = acc[u] * rinv;
        op[(size_t)row * FOUT] = (sx > 0.f) ? sx : expm1f(sx);
    }
}

extern "C" void kernel_launch(void* const* d_in, const int* in_sizes, int n_in,
                              void* d_out, int out_size, void* d_ws, size_t ws_size,
                              hipStream_t stream) {
    const float* x   = (const float*)d_in[0];   // [B,N,128]
    const int*   adj = (const int*)d_in[1];     // [B,N,N]
    const float* W   = (const float*)d_in[2];   // [128,64]
    const float* a   = (const float*)d_in[3];   // [128,1]
    float* out = (float*)d_out;                 // [B,N,64]

    unsigned short* ht = (unsigned short*)d_ws;          // [B][64][2048] bf16, 2.1 MB
    float* f1   = (float*)(ht + (size_t)BB * FOUT * NN); // B*N
    float* f2   = f1 + (size_t)BB * NN;                  // B*N

    gat_k1<<<dim3(BB * NN / 16), dim3(256), 0, stream>>>(x, W, a, ht, f1, f2);
    gat_k2f<<<dim3(NN / TI, BB), dim3(256), 0, stream>>>(adj, ht, f1, f2, out);
}

// Round 16
// 221.984 us; speedup vs baseline: 1.0458x; 1.0458x over previous
//
#include <hip/hip_runtime.h>
#include <math.h>

#define BB 8
#define NN 2048
#define FIN 128
#define FOUT 64
#define TI 16
#define TJ 256
#define TJP (TJ + 8)      // +8 bf16 = 16B row pad (same skew family as verified)
#define NTILE (NN / TJ)   // 8 j-tiles, looped inside the block

typedef short bf16x8 __attribute__((ext_vector_type(8)));
typedef float f32x4 __attribute__((ext_vector_type(4)));

// exp(tanh(z)) = exp((u-1)/(u+1)), u = e^{2z}; v_rcp instead of precise div.
__device__ __forceinline__ float exp_tanh(float z) {
    float zc = fminf(fmaxf(z, -15.f), 15.f);
    float u = __expf(zc + zc);
    float tn = (u - 1.f) * __builtin_amdgcn_rcpf(u + 1.f);
    return __expf(tn);
}

__device__ __forceinline__ unsigned short f2bf(float x) {
    union { float f; unsigned u; } v; v.f = x;
    unsigned r = v.u + 0x7FFF + ((v.u >> 16) & 1);   // round-to-nearest-even
    return (unsigned short)(r >> 16);
}

// K1: h = x @ W -> bf16 TRANSPOSED ht[b][c][n]; f1 = h.a1, f2 = h.a2.
// (verbatim from the harness-verified kernel)
__global__ __launch_bounds__(256, 2) void gat_k1(const float* __restrict__ x,
                                                 const float* __restrict__ W,
                                                 const float* __restrict__ a,
                                                 unsigned short* __restrict__ ht,
                                                 float* __restrict__ f1,
                                                 float* __restrict__ f2) {
    __shared__ __attribute__((aligned(16))) float Wl[FIN][FOUT];  // 32 KB
    __shared__ __attribute__((aligned(16))) float xs[16][FIN];    // 8 KB
    int t = threadIdx.x;

    const float4* W4 = (const float4*)W;
    float4* Wl4 = (float4*)&Wl[0][0];
#pragma unroll
    for (int kk = 0; kk < 8; ++kk) Wl4[t + 256 * kk] = W4[t + 256 * kk];

    size_t row0 = (size_t)blockIdx.x * 16;
    const float4* x4 = (const float4*)(x + row0 * FIN);
    float4* xs4 = (float4*)&xs[0][0];
#pragma unroll
    for (int kk = 0; kk < 2; ++kk) xs4[t + 256 * kk] = x4[t + 256 * kk];
    __syncthreads();

    int c = t & 63;
    int rq = t >> 6;
    float acc[4] = {0.f, 0.f, 0.f, 0.f};
#pragma unroll 8
    for (int k = 0; k < FIN; ++k) {
        float wv = Wl[k][c];
        acc[0] = fmaf(xs[rq][k], wv, acc[0]);
        acc[1] = fmaf(xs[rq + 4][k], wv, acc[1]);
        acc[2] = fmaf(xs[rq + 8][k], wv, acc[2]);
        acc[3] = fmaf(xs[rq + 12][k], wv, acc[3]);
    }
    float a1c = a[c], a2c = a[FOUT + c];
#pragma unroll
    for (int m = 0; m < 4; ++m) {
        size_t bn = row0 + rq + 4 * m;
        int b = (int)(bn >> 11);
        int n = (int)(bn & 2047);
        ht[((size_t)b * FOUT + c) * NN + n] = f2bf(acc[m]);
        float p1 = acc[m] * a1c;
        float p2 = acc[m] * a2c;
#pragma unroll
        for (int off = 32; off > 0; off >>= 1) {
            p1 += __shfl_down(p1, off, 64);
            p2 += __shfl_down(p2, off, 64);
        }
        if (c == 0) { f1[bn] = p1; f2[bn] = p2; }
    }
}

// K2f R18: R16 fused structure, TJ 512->256, prefetch REVERTED.
// Evidence ledger: R15 adj-bits (-97% traffic) = +28us -> not BW-bound.
// R16 atomics/k3/memset deleted = -4 -> not epilogue-bound. R17 reg
// prefetch = +4.5 -> compiler's vmcnt(0)-before-s_barrier drains the
// prefetch (m97 semantics), register pipelining across __syncthreads is
// void. COUNTERS (R17): MfmaUtil 1.4%, VALUBusy 16%, HBM 8%, Occupancy
// 22% (~7 waves/CU) -- pure latency-serialization, under-resident. All
// four k2 variants (114-119us) shared ~19KB LDS + ~96 VGPR: same
// residency cap every time. THIS delta: halve the tile -> pb 8.25 KB
// (block ~9.6 KB LDS), avreg[4] (-16 VGPR), est <=72 VGPR -> ~2x more
// resident blocks to cover the per-tile barrier-drain stalls.
// Mapping at TJ=256: thread t -> j4 = t&63 (float4 col group), wave
// w = t>>6 owns rows {w, w+4, w+8, w+12}; 64 lanes x 64 j4-groups cover
// the full 256-col row; rowsum reduce = shfl within the owning wave.
__global__ __launch_bounds__(256) void gat_k2f(const int* __restrict__ adj,
                                               const unsigned short* __restrict__ ht,
                                               const float* __restrict__ f1,
                                               const float* __restrict__ f2,
                                               float* __restrict__ out) {
    __shared__ __attribute__((aligned(16))) unsigned short pb[TI][TJP];  // 8.25 KB
    __shared__ __attribute__((aligned(16))) float f2s[TJ];               // 1 KB
    __shared__ float f1s[TI];
    __shared__ float rsw[TI];                                            // 64 B

    int t = threadIdx.x;
    int i0 = blockIdx.x * TI;
    int b = blockIdx.y;

    int lane = t & 63;
    int w = t >> 6;         // wave id -> MFMA c-tile AND p-phase row group
    int mrow = lane & 15;   // MFMA m / n index
    int quad = lane >> 4;   // MFMA k-quad

    int j4 = t & 63;        // float4 col group within the 256-wide tile

    if (t < TI) f1s[t] = f1[(size_t)b * NN + i0 + t];
    __syncthreads();

    float f1r[4];
    float ps[4];
#pragma unroll
    for (int m = 0; m < 4; ++m) {
        f1r[m] = f1s[w + 4 * m];
        ps[m] = 0.f;
    }
    f32x4 acc = {0.f, 0.f, 0.f, 0.f};

    // per-thread adj base: rows (i0 + w + 4m), col group 4*j4
    const int* adjrow = adj + (((size_t)b * NN + i0) * NN) + 4 * j4;

    for (int jt = 0; jt < NTILE; ++jt) {
        int j0 = jt * TJ;

        // adj loads for this tile (issue first; covered by f2 stage + barrier)
        int4 avreg[4];
#pragma unroll
        for (int m = 0; m < 4; ++m)
            avreg[m] = *(const int4*)(adjrow + (size_t)(w + 4 * m) * NN + j0);

        // stage this j-tile's f2 slice (256 floats, one per thread)
        f2s[t] = f2[(size_t)b * NN + j0 + t];
        __syncthreads();   // WAR barrier for pb/f2s reuse (R16-verified order)

        // ---- p-phase: mask -> exp(tanh) -> bf16 into LDS ----
        float4 fv = ((const float4*)f2s)[j4];
#pragma unroll
        for (int m = 0; m < 4; ++m) {
            int4 av = avreg[m];
            float f1i = f1r[m];
            float4 p;
            p.x = (av.x > 0) ? exp_tanh(f1i + fv.x) : 0.f;
            p.y = (av.y > 0) ? exp_tanh(f1i + fv.y) : 0.f;
            p.z = (av.z > 0) ? exp_tanh(f1i + fv.z) : 0.f;
            p.w = (av.w > 0) ? exp_tanh(f1i + fv.w) : 0.f;
            ps[m] += p.x + p.y + p.z + p.w;   // running rowsum across jt
            ushort4 pk;
            pk.x = f2bf(p.x); pk.y = f2bf(p.y);
            pk.z = f2bf(p.z); pk.w = f2bf(p.w);
            *(ushort4*)&pb[w + 4 * m][4 * j4] = pk;
        }
        __syncthreads();

        // ---- PV on matrix pipe: 8 chunks of K=32, acc chained over jt ----
        const unsigned short* hp =
            ht + ((size_t)b * FOUT + w * 16 + mrow) * NN + j0 + 8 * quad;
        const unsigned short* prow = &pb[mrow][8 * quad];
#pragma unroll
        for (int ch = 0; ch < TJ / 32; ++ch) {
            bf16x8 af = *(const bf16x8*)(prow + 32 * ch);
            bf16x8 bf = *(const bf16x8*)(hp + 32 * ch);
            acc = __builtin_amdgcn_mfma_f32_16x16x32_bf16(af, bf, acc, 0, 0, 0);
        }
    }

    // ---- rowsum: wave w owns rows w+4m exclusively -> one LDS write each ----
#pragma unroll
    for (int m = 0; m < 4; ++m) {
        float s = ps[m];
#pragma unroll
        for (int off = 32; off > 0; off >>= 1) s += __shfl_down(s, off, 64);
        if (lane == 0) rsw[w + 4 * m] = s;
    }
    __syncthreads();

    // ---- epilogue: final out = elu(acc / rowsum), D-frag mapping verified ----
    float* op = out + ((size_t)b * NN + i0) * FOUT + w * 16 + mrow;
#pragma unroll
    for (int u = 0; u < 4; ++u) {
        int row = quad * 4 + u;
        float rinv = __builtin_amdgcn_rcpf(rsw[row]);
        float sx = acc[u] * rinv;
        op[(size_t)row * FOUT] = (sx > 0.f) ? sx : expm1f(sx);
    }
}

extern "C" void kernel_launch(void* const* d_in, const int* in_sizes, int n_in,
                              void* d_out, int out_size, void* d_ws, size_t ws_size,
                              hipStream_t stream) {
    const float* x   = (const float*)d_in[0];   // [B,N,128]
    const int*   adj = (const int*)d_in[1];     // [B,N,N]
    const float* W   = (const float*)d_in[2];   // [128,64]
    const float* a   = (const float*)d_in[3];   // [128,1]
    float* out = (float*)d_out;                 // [B,N,64]

    unsigned short* ht = (unsigned short*)d_ws;          // [B][64][2048] bf16, 2.1 MB
    float* f1   = (float*)(ht + (size_t)BB * FOUT * NN); // B*N
    float* f2   = f1 + (size_t)BB * NN;                  // B*N

    gat_k1<<<dim3(BB * NN / 16), dim3(256), 0, stream>>>(x, W, a, ht, f1, f2);
    gat_k2f<<<dim3(NN / TI, BB), dim3(256), 0, stream>>>(adj, ht, f1, f2, out);
}